// Round 10
// baseline (8851.536 us; speedup 1.0000x reference)
//
#include <hip/hip_runtime.h>
#include <hip/hip_bf16.h>
#include <hip/hip_fp16.h>

// Problem constants (fixed by the reference)
#define H_SHEET 150
#define W_SHEET 300
#define NN      (H_SHEET * W_SHEET)   // 45000
#define KSYN    32
#define KP1     33
#define NNZ     (NN * KP1)            // 1,485,000
#define BATCH   32
#define TSTEPS  100
#define NPAD    45056                 // N padded for alignment
#define NCHUNK  64
#define NPART   ((NN + NCHUNK - 1) / NCHUNK)   // 704
#define LONG_THRESH 64                 // rows with more entries go to long path

typedef float vf4 __attribute__((ext_vector_type(4)));

// Persistent geometry: 704 blocks x 512 threads (8 waves). launch_bounds(512,6)
// -> >=6 waves/SIMD -> 3 blocks/CU capacity -> 768 slots >= 704 blocks:
// co-residency guaranteed. 64 row-slots per block x 704 = 45056 rows.
#define PBLOCKS      704
#define PTHREADS     512
#define ROWS_PER_PB  64

// ---------------------------------------------------------------------------
// bijective XCD swizzle (8 XCDs): contiguous grid chunk per XCD
__device__ inline int xcd_swizzle(int bid, int nwg) {
    int q = nwg >> 3, r = nwg & 7;
    int xcd = bid & 7, idx = bid >> 3;
    return (xcd < r ? xcd * (q + 1) : r * (q + 1) + (xcd - r) * q) + idx;
}

// packed 4B entry: low 16 = (i16)(col - destrow), high 16 = fp16 weight
__device__ inline float unpack_val(unsigned int e) {
    return __half2float(__ushort_as_half((unsigned short)(e >> 16)));
}
__device__ inline int unpack_col(unsigned int e, int r) {
    return r + (int)(short)(unsigned short)(e & 0xffffu);
}

// ---------------------------------------------------------------------------
// 1) Histogram of destination rows
__global__ __launch_bounds__(256) void hist_kernel(const int* __restrict__ rows,
                                                   int* __restrict__ counts) {
    int e = blockIdx.x * 256 + threadIdx.x;
    if (e < NNZ) atomicAdd(&counts[rows[e]], 1);
}

// ---------------------------------------------------------------------------
// 2) Exclusive scan of counts -> row_ptr (single block, 1024 threads)
__global__ __launch_bounds__(1024) void scan_kernel(const int* __restrict__ counts,
                                                    int* __restrict__ row_ptr) {
    __shared__ int wsum[16];
    __shared__ int carry_s;
    const int lane = threadIdx.x & 63;
    const int wid  = threadIdx.x >> 6;
    if (threadIdx.x == 0) carry_s = 0;
    __syncthreads();
    for (int base = 0; base < NN; base += 1024) {
        int i = base + threadIdx.x;
        int v = (i < NN) ? counts[i] : 0;
        int incl = v;
        #pragma unroll
        for (int d = 1; d < 64; d <<= 1) {
            int t = __shfl_up(incl, d, 64);
            if (lane >= d) incl += t;
        }
        if (lane == 63) wsum[wid] = incl;
        __syncthreads();
        if (wid == 0 && lane < 16) {
            int s = wsum[lane];
            #pragma unroll
            for (int d = 1; d < 16; d <<= 1) {
                int t = __shfl_up(s, d, 64);
                if (lane >= d) s += t;
            }
            wsum[lane] = s;
        }
        __syncthreads();
        int wprev = (wid > 0) ? wsum[wid - 1] : 0;
        int total = carry_s + wprev + incl;
        if (i < NN) row_ptr[i + 1] = total;
        __syncthreads();
        if (threadIdx.x == 1023) carry_s += wsum[15];
        __syncthreads();
    }
    if (threadIdx.x == 0) row_ptr[0] = 0;
}

// ---------------------------------------------------------------------------
// 3) Scatter entries into packed CSR (col computed as e/33; cols input unused)
__global__ __launch_bounds__(256) void scatter_kernel(const int* __restrict__ rows,
                                                      const float* __restrict__ vals,
                                                      int* __restrict__ cursor,
                                                      unsigned int* __restrict__ csr4) {
    int e = blockIdx.x * 256 + threadIdx.x;
    if (e >= NNZ) return;
    int r = rows[e];
    int pos = atomicAdd(&cursor[r], 1);
    int col = e / KP1;
    int d = col - r;
    unsigned short hv = __half_as_ushort(__float2half(vals[e]));
    csr4[pos] = (unsigned int)(unsigned short)(short)d | ((unsigned int)hv << 16);
}

// ---------------------------------------------------------------------------
// 3b) Classify long rows (n > LONG_THRESH) into a list
__global__ __launch_bounds__(256) void classify_kernel(const int* __restrict__ row_ptr,
                                                       int* __restrict__ long_list,
                                                       int* __restrict__ long_cnt) {
    int r = blockIdx.x * 256 + threadIdx.x;
    if (r >= NN) return;
    int n = row_ptr[r + 1] - row_ptr[r];
    if (n > LONG_THRESH) long_list[atomicAdd(long_cnt, 1)] = r;
}

// ---------------------------------------------------------------------------
// 4) h0 = x.T via LDS tile transpose: x (B,N) -> h (N,B). Tile 64n x 32b.
__global__ __launch_bounds__(256) void init_kernel(const float* __restrict__ x,
                                                   float* __restrict__ h) {
    __shared__ float tile[64 * 33];
    int n0 = blockIdx.x * 64;
    int tn = threadIdx.x & 63;
    int tb = threadIdx.x >> 6;
    #pragma unroll
    for (int p = 0; p < 8; ++p) {
        int b = tb + p * 4;
        int n = n0 + tn;
        float v = (n < NN) ? x[b * NN + n] : 0.f;
        tile[tn * 33 + b] = v;
    }
    __syncthreads();
    int b2 = threadIdx.x & 31;
    int nb = threadIdx.x >> 5;
    #pragma unroll
    for (int p = 0; p < 8; ++p) {
        int n = n0 + nb + p * 8;
        if (n < NN) h[n * 32 + b2] = tile[(nb + p * 8) * 33 + b2];
    }
}

// ---------------------------------------------------------------------------
// 5) Persistent RNN: all 100 steps, device-wide barrier per step.
//    Barrier discipline (round-3 fix): thread-0-only release-RMW arrive,
//    RELAXED RMW poll (always served at coherent point -> no stale spin,
//    no per-poll invalidate), then ONE acquire fence per block.
__global__ __launch_bounds__(PTHREADS, 6) void rnn_persistent(
        const int* __restrict__ row_ptr, const unsigned int* __restrict__ csr4,
        const float* __restrict__ bias, float* __restrict__ hA,
        float* __restrict__ hB, const int* __restrict__ long_list,
        const int* __restrict__ long_cnt, int* __restrict__ bar) {
    __shared__ vf4 red[PTHREADS];

    const int blk   = xcd_swizzle(blockIdx.x, PBLOCKS);
    const int slot  = threadIdx.x >> 3;         // 0..63 row slot
    const int lane8 = threadIdx.x & 7;
    const int bo    = lane8 * 4;
    const int r     = blk * ROWS_PER_PB + slot;

    // hoisted per-row invariants (loaded once for all 100 steps)
    bool active = (r < NN);
    int s = 0, n = 0;
    float bv = 0.f;
    if (active) {
        s  = row_ptr[r];
        n  = row_ptr[r + 1] - s;
        bv = bias[r];
        if (n > LONG_THRESH) active = false;    // long path covers it
    }
    const unsigned int* __restrict__ p = csr4 + s;
    const int lcnt = *long_cnt;

    for (int t = 0; t < TSTEPS; ++t) {
        const float* __restrict__ hin  = (t & 1) ? hB : hA;
        float*       __restrict__ hout = (t & 1) ? hA : hB;

        // ---------------- short rows ----------------
        if (active) {
            vf4 accA = (vf4)(0.f);
            vf4 accB = (vf4)(0.f);
            int i = 0;
            for (; i + 8 <= n; i += 8) {
                unsigned int e0 = p[i];
                unsigned int e1 = p[i + 1];
                unsigned int e2 = p[i + 2];
                unsigned int e3 = p[i + 3];
                unsigned int e4 = p[i + 4];
                unsigned int e5 = p[i + 5];
                unsigned int e6 = p[i + 6];
                unsigned int e7 = p[i + 7];
                vf4 h0 = *(const vf4*)&hin[(unpack_col(e0, r) << 5) + bo];
                vf4 h1 = *(const vf4*)&hin[(unpack_col(e1, r) << 5) + bo];
                vf4 h2 = *(const vf4*)&hin[(unpack_col(e2, r) << 5) + bo];
                vf4 h3 = *(const vf4*)&hin[(unpack_col(e3, r) << 5) + bo];
                vf4 h4 = *(const vf4*)&hin[(unpack_col(e4, r) << 5) + bo];
                vf4 h5 = *(const vf4*)&hin[(unpack_col(e5, r) << 5) + bo];
                vf4 h6 = *(const vf4*)&hin[(unpack_col(e6, r) << 5) + bo];
                vf4 h7 = *(const vf4*)&hin[(unpack_col(e7, r) << 5) + bo];
                accA += unpack_val(e0) * h0;
                accB += unpack_val(e1) * h1;
                accA += unpack_val(e2) * h2;
                accB += unpack_val(e3) * h3;
                accA += unpack_val(e4) * h4;
                accB += unpack_val(e5) * h5;
                accA += unpack_val(e6) * h6;
                accB += unpack_val(e7) * h7;
            }
            for (; i < n; ++i) {
                unsigned int e0 = p[i];
                vf4 hv = *(const vf4*)&hin[(unpack_col(e0, r) << 5) + bo];
                accA += unpack_val(e0) * hv;
            }
            vf4 acc = accA + accB;
            vf4 o;
            o.x = fmaxf(acc.x + bv, 0.f);
            o.y = fmaxf(acc.y + bv, 0.f);
            o.z = fmaxf(acc.z + bv, 0.f);
            o.w = fmaxf(acc.w + bv, 0.f);
            *(vf4*)&hout[(r << 5) + bo] = o;
        }

        // ---------------- long rows (grid-stride, whole block each) ------
        for (int li = (int)blockIdx.x; li < lcnt; li += PBLOCKS) {
            int lr = long_list[li];
            int ls = row_ptr[lr];
            int ln = row_ptr[lr + 1] - ls;
            const unsigned int* __restrict__ lp = csr4 + ls;
            int g = threadIdx.x >> 3;            // 64 entry groups
            vf4 a = (vf4)(0.f);
            for (int i = g; i < ln; i += 64) {
                unsigned int e0 = lp[i];
                vf4 hv = *(const vf4*)&hin[(unpack_col(e0, lr) << 5) + bo];
                a += unpack_val(e0) * hv;
            }
            red[threadIdx.x] = a;
            __syncthreads();
            if (threadIdx.x < 128) {
                red[threadIdx.x] = red[threadIdx.x] + red[threadIdx.x + 128] +
                                   red[threadIdx.x + 256] + red[threadIdx.x + 384];
            }
            __syncthreads();
            if (threadIdx.x < 8) {
                vf4 aa = (vf4)(0.f);
                #pragma unroll
                for (int k = 0; k < 16; ++k) aa += red[k * 8 + threadIdx.x];
                float lbv = bias[lr];
                vf4 o;
                o.x = fmaxf(aa.x + lbv, 0.f);
                o.y = fmaxf(aa.y + lbv, 0.f);
                o.z = fmaxf(aa.z + lbv, 0.f);
                o.w = fmaxf(aa.w + lbv, 0.f);
                *(vf4*)&hout[(lr << 5) + threadIdx.x * 4] = o;
            }
            __syncthreads();
        }

        // ---------------- device-wide barrier ----------------
        if (t + 1 < TSTEPS) {
            __syncthreads();                     // drains all waves' stores
            if (threadIdx.x == 0) {
                // release: wb local L2 + RMW at coherent point
                __hip_atomic_fetch_add(&bar[t], 1, __ATOMIC_RELEASE,
                                       __HIP_MEMORY_SCOPE_AGENT);
                // relaxed RMW poll: always fresh, no invalidate storm
                while (__hip_atomic_fetch_add(&bar[t], 0, __ATOMIC_RELAXED,
                                              __HIP_MEMORY_SCOPE_AGENT) < PBLOCKS)
                    __builtin_amdgcn_s_sleep(8);
                // single acquire: invalidate L1/L2 once per block
                __builtin_amdgcn_fence(__ATOMIC_ACQUIRE, "agent");
            }
            __syncthreads();
        }
    }
}

// ---------------------------------------------------------------------------
// 6a) Split-K GEMM partials
__global__ __launch_bounds__(256) void gemm1_kernel(const float* __restrict__ h,
                                                    const float* __restrict__ w1,
                                                    float* __restrict__ partials) {
    int n0 = blockIdx.x * NCHUNK;
    int nend = n0 + NCHUNK; if (nend > NN) nend = NN;
    int j  = threadIdx.x & 63;
    int b0 = threadIdx.x >> 6;
    float sum[8];
    #pragma unroll
    for (int ii = 0; ii < 8; ++ii) sum[ii] = 0.f;
    for (int n = n0; n < nend; ++n) {
        float w = w1[n * 64 + j];
        #pragma unroll
        for (int ii = 0; ii < 8; ++ii)
            sum[ii] = fmaf(w, h[n * 32 + b0 + ii * 4], sum[ii]);
    }
    float* dst = partials + blockIdx.x * 2048;
    #pragma unroll
    for (int ii = 0; ii < 8; ++ii)
        dst[(b0 + ii * 4) * 64 + j] = sum[ii];
}

// 6b) Reduce partials -> acc (2048 cells)
__global__ __launch_bounds__(256) void gemm1_reduce(const float* __restrict__ partials,
                                                    float* __restrict__ acc) {
    int cell = blockIdx.x * 256 + threadIdx.x;
    float s0 = 0.f, s1 = 0.f, s2 = 0.f, s3 = 0.f;
    int k = 0;
    for (; k + 4 <= NPART; k += 4) {
        s0 += partials[(k + 0) * 2048 + cell];
        s1 += partials[(k + 1) * 2048 + cell];
        s2 += partials[(k + 2) * 2048 + cell];
        s3 += partials[(k + 3) * 2048 + cell];
    }
    for (; k < NPART; ++k) s0 += partials[k * 2048 + cell];
    acc[cell] = (s0 + s1) + (s2 + s3);
}

// ---------------------------------------------------------------------------
// 7) Head
__global__ __launch_bounds__(320) void head_kernel(const float* __restrict__ acc,
                                                   const float* __restrict__ b1,
                                                   const float* __restrict__ w2,
                                                   const float* __restrict__ b2,
                                                   float* __restrict__ out) {
    int t = threadIdx.x;
    if (t >= 320) return;
    int b = t / 10, oj = t % 10;
    float s = b2[oj];
    #pragma unroll
    for (int k = 0; k < 64; ++k)
        s += fmaxf(acc[b * 64 + k] + b1[k], 0.f) * w2[k * 10 + oj];
    out[b * 10 + oj] = s;
}

// ---------------------------------------------------------------------------
extern "C" void kernel_launch(void* const* d_in, const int* in_sizes, int n_in,
                              void* d_out, int out_size, void* d_ws, size_t ws_size,
                              hipStream_t stream) {
    const float* x    = (const float*)d_in[0];
    const float* vals = (const float*)d_in[1];
    const float* bias = (const float*)d_in[2];
    const float* w1   = (const float*)d_in[3];
    const float* b1   = (const float*)d_in[4];
    const float* w2   = (const float*)d_in[5];
    const float* b2   = (const float*)d_in[6];
    const int*   rows = (const int*)d_in[7];
    float* out = (float*)d_out;

    // workspace layout
    const int NB = NN * BATCH;                    // 1,440,000 floats
    float*        hA        = (float*)d_ws;
    float*        hB        = hA + NB;
    int*          row_ptr   = (int*)(hB + NB);            // NPAD ints
    int*          cursor    = row_ptr + NPAD;             // NPAD ints
    unsigned int* csr4      = (unsigned int*)(cursor + NPAD);  // NNZ u32
    float*        partials  = (float*)(csr4 + NNZ);       // NPART*2048 floats
    float*        acc       = partials + NPART * 2048;    // 2048 floats
    int*          long_cnt  = (int*)(acc + 2048);         // 1 int
    int*          long_list = long_cnt + 8;               // NPAD ints
    int*          bar       = long_list + NPAD;           // TSTEPS ints

    // ---- CSR-transpose build ----
    hipMemsetAsync(cursor, 0, NN * sizeof(int), stream);
    hipMemsetAsync(long_cnt, 0, sizeof(int), stream);
    hipMemsetAsync(bar, 0, TSTEPS * sizeof(int), stream);
    hist_kernel<<<(NNZ + 255) / 256, 256, 0, stream>>>(rows, cursor);
    scan_kernel<<<1, 1024, 0, stream>>>(cursor, row_ptr);
    hipMemcpyAsync(cursor, row_ptr, NN * sizeof(int), hipMemcpyDeviceToDevice, stream);
    scatter_kernel<<<(NNZ + 255) / 256, 256, 0, stream>>>(rows, vals, cursor, csr4);
    classify_kernel<<<(NN + 255) / 256, 256, 0, stream>>>(row_ptr, long_list, long_cnt);

    // ---- h0 = x.T ----
    init_kernel<<<(NN + 63) / 64, 256, 0, stream>>>(x, hA);

    // ---- all T steps in one persistent kernel ----
    rnn_persistent<<<PBLOCKS, PTHREADS, 0, stream>>>(
        row_ptr, csr4, bias, hA, hB, long_list, long_cnt, bar);
    float* hfin = hA;   // TSTEPS even -> final state in hA

    // ---- MLP head ----
    gemm1_kernel<<<NPART, 256, 0, stream>>>(hfin, w1, partials);
    gemm1_reduce<<<8, 256, 0, stream>>>(partials, acc);
    head_kernel<<<1, 320, 0, stream>>>(acc, b1, w2, b2, out);
}

// Round 11
// 2462.607 us; speedup vs baseline: 3.5944x; 3.5944x over previous
//
#include <hip/hip_runtime.h>
#include <hip/hip_bf16.h>
#include <hip/hip_fp16.h>

// Problem constants (fixed by the reference)
#define H_SHEET 150
#define W_SHEET 300
#define NN      (H_SHEET * W_SHEET)   // 45000
#define KSYN    32
#define KP1     33
#define NNZ     (NN * KP1)            // 1,485,000
#define BATCH   32
#define TSTEPS  100
#define NPAD    45056                 // N padded for alignment
#define NCHUNK  64
#define NPART   ((NN + NCHUNK - 1) / NCHUNK)   // 704
#define LONG_THRESH 64                 // rows with more entries go to long path

typedef float vf4 __attribute__((ext_vector_type(4)));

// step-kernel geometry: EXACTLY 8192 waves = one dispatch round on 256 CUs.
#define ROWS_PER_BLOCK 32
#define SGRID ((NN + ROWS_PER_BLOCK - 1) / ROWS_PER_BLOCK)   // 1407 short blocks
#define STEP_BLOCKS 2048
#define LGRID (STEP_BLOCKS - SGRID)                          // 641 long blocks

// ---------------------------------------------------------------------------
// bijective XCD swizzle (8 XCDs): contiguous grid chunk per XCD
__device__ inline int xcd_swizzle(int bid, int nwg) {
    int q = nwg >> 3, r = nwg & 7;
    int xcd = bid & 7, idx = bid >> 3;
    return (xcd < r ? xcd * (q + 1) : r * (q + 1) + (xcd - r) * q) + idx;
}

// packed 4B entry: low 16 = (i16)(col - destrow), high 16 = fp16 weight
__device__ inline float unpack_val(unsigned int e) {
    return __half2float(__ushort_as_half((unsigned short)(e >> 16)));
}
__device__ inline int unpack_col(unsigned int e, int r) {
    return r + (int)(short)(unsigned short)(e & 0xffffu);
}

// ---------------------------------------------------------------------------
// 1) Histogram of destination rows
__global__ __launch_bounds__(256) void hist_kernel(const int* __restrict__ rows,
                                                   int* __restrict__ counts) {
    int e = blockIdx.x * 256 + threadIdx.x;
    if (e < NNZ) atomicAdd(&counts[rows[e]], 1);
}

// ---------------------------------------------------------------------------
// 2) Exclusive scan of counts -> row_ptr (single block, 1024 threads)
__global__ __launch_bounds__(1024) void scan_kernel(const int* __restrict__ counts,
                                                    int* __restrict__ row_ptr) {
    __shared__ int wsum[16];
    __shared__ int carry_s;
    const int lane = threadIdx.x & 63;
    const int wid  = threadIdx.x >> 6;
    if (threadIdx.x == 0) carry_s = 0;
    __syncthreads();
    for (int base = 0; base < NN; base += 1024) {
        int i = base + threadIdx.x;
        int v = (i < NN) ? counts[i] : 0;
        int incl = v;
        #pragma unroll
        for (int d = 1; d < 64; d <<= 1) {
            int t = __shfl_up(incl, d, 64);
            if (lane >= d) incl += t;
        }
        if (lane == 63) wsum[wid] = incl;
        __syncthreads();
        if (wid == 0 && lane < 16) {
            int s = wsum[lane];
            #pragma unroll
            for (int d = 1; d < 16; d <<= 1) {
                int t = __shfl_up(s, d, 64);
                if (lane >= d) s += t;
            }
            wsum[lane] = s;
        }
        __syncthreads();
        int wprev = (wid > 0) ? wsum[wid - 1] : 0;
        int total = carry_s + wprev + incl;
        if (i < NN) row_ptr[i + 1] = total;
        __syncthreads();
        if (threadIdx.x == 1023) carry_s += wsum[15];
        __syncthreads();
    }
    if (threadIdx.x == 0) row_ptr[0] = 0;
}

// ---------------------------------------------------------------------------
// 3) Scatter entries into packed CSR (col computed as e/33; cols input unused)
__global__ __launch_bounds__(256) void scatter_kernel(const int* __restrict__ rows,
                                                      const float* __restrict__ vals,
                                                      int* __restrict__ cursor,
                                                      unsigned int* __restrict__ csr4) {
    int e = blockIdx.x * 256 + threadIdx.x;
    if (e >= NNZ) return;
    int r = rows[e];
    int pos = atomicAdd(&cursor[r], 1);
    int col = e / KP1;
    int d = col - r;
    unsigned short hv = __half_as_ushort(__float2half(vals[e]));
    csr4[pos] = (unsigned int)(unsigned short)(short)d | ((unsigned int)hv << 16);
}

// ---------------------------------------------------------------------------
// 3b) Classify long rows (n > LONG_THRESH) into a list
__global__ __launch_bounds__(256) void classify_kernel(const int* __restrict__ row_ptr,
                                                       int* __restrict__ long_list,
                                                       int* __restrict__ long_cnt) {
    int r = blockIdx.x * 256 + threadIdx.x;
    if (r >= NN) return;
    int n = row_ptr[r + 1] - row_ptr[r];
    if (n > LONG_THRESH) long_list[atomicAdd(long_cnt, 1)] = r;
}

// ---------------------------------------------------------------------------
// 4) h0 = x.T via LDS tile transpose: x (B,N) -> h (N,B). Tile 64n x 32b.
__global__ __launch_bounds__(256) void init_kernel(const float* __restrict__ x,
                                                   float* __restrict__ h) {
    __shared__ float tile[64 * 33];
    int n0 = blockIdx.x * 64;
    int tn = threadIdx.x & 63;
    int tb = threadIdx.x >> 6;
    #pragma unroll
    for (int p = 0; p < 8; ++p) {
        int b = tb + p * 4;
        int n = n0 + tn;
        float v = (n < NN) ? x[b * NN + n] : 0.f;
        tile[tn * 33 + b] = v;
    }
    __syncthreads();
    int b2 = threadIdx.x & 31;
    int nb = threadIdx.x >> 5;
    #pragma unroll
    for (int p = 0; p < 8; ++p) {
        int n = n0 + nb + p * 8;
        if (n < NN) h[n * 32 + b2] = tile[(nb + p * 8) * 33 + b2];
    }
}

// ---------------------------------------------------------------------------
// 5) One RNN step. Streaming prefetch of h_in + csr4 (coalesced, sunk via asm)
//    converts the dependent gather chains from HBM-latency to cache-latency.
//    blocks [0, SGRID): short rows (n<=64), 8 lanes/row, unroll x8.
//    blocks [SGRID, STEP_BLOCKS): long rows, whole block each, grid-stride.
__global__ __launch_bounds__(256) void step_kernel(const int* __restrict__ row_ptr,
                                                   const unsigned int* __restrict__ csr4,
                                                   const float* __restrict__ bias,
                                                   const float* __restrict__ h_in,
                                                   float* __restrict__ h_out,
                                                   const int* __restrict__ long_list,
                                                   const int* __restrict__ long_cnt) {
    // ---- streaming prefetch: pull h_in (5.76 MB) + csr4 (5.94 MB) toward
    //      L2/L3 at full coalesced BW before the latency chains start.
    {
        int tid = blockIdx.x * 256 + threadIdx.x;
        if (tid < (NN * BATCH / 4)) {
            vf4 v = ((const vf4*)h_in)[tid];
            asm volatile("" :: "v"(v.x), "v"(v.y), "v"(v.z), "v"(v.w));
        }
        if (tid < (NNZ / 4)) {
            uint4 c = ((const uint4*)csr4)[tid];
            asm volatile("" :: "v"(c.x), "v"(c.y), "v"(c.z), "v"(c.w));
        }
    }

    if (blockIdx.x < SGRID) {
        // ---------------- short path ----------------
        int blk = xcd_swizzle(blockIdx.x, SGRID);
        int r = blk * ROWS_PER_BLOCK + (threadIdx.x >> 3);
        if (r >= NN) return;
        int bo = (threadIdx.x & 7) * 4;

        int s = row_ptr[r];
        int e = row_ptr[r + 1];
        int n = e - s;
        if (n > LONG_THRESH) return;          // handled by long path
        const unsigned int* __restrict__ p = csr4 + s;

        vf4 accA = (vf4)(0.f);
        vf4 accB = (vf4)(0.f);
        int i = 0;
        for (; i + 8 <= n; i += 8) {
            unsigned int e0 = p[i];
            unsigned int e1 = p[i + 1];
            unsigned int e2 = p[i + 2];
            unsigned int e3 = p[i + 3];
            unsigned int e4 = p[i + 4];
            unsigned int e5 = p[i + 5];
            unsigned int e6 = p[i + 6];
            unsigned int e7 = p[i + 7];
            vf4 h0 = *(const vf4*)&h_in[(unpack_col(e0, r) << 5) + bo];
            vf4 h1 = *(const vf4*)&h_in[(unpack_col(e1, r) << 5) + bo];
            vf4 h2 = *(const vf4*)&h_in[(unpack_col(e2, r) << 5) + bo];
            vf4 h3 = *(const vf4*)&h_in[(unpack_col(e3, r) << 5) + bo];
            vf4 h4 = *(const vf4*)&h_in[(unpack_col(e4, r) << 5) + bo];
            vf4 h5 = *(const vf4*)&h_in[(unpack_col(e5, r) << 5) + bo];
            vf4 h6 = *(const vf4*)&h_in[(unpack_col(e6, r) << 5) + bo];
            vf4 h7 = *(const vf4*)&h_in[(unpack_col(e7, r) << 5) + bo];
            accA += unpack_val(e0) * h0;
            accB += unpack_val(e1) * h1;
            accA += unpack_val(e2) * h2;
            accB += unpack_val(e3) * h3;
            accA += unpack_val(e4) * h4;
            accB += unpack_val(e5) * h5;
            accA += unpack_val(e6) * h6;
            accB += unpack_val(e7) * h7;
        }
        for (; i < n; ++i) {
            unsigned int e0 = p[i];
            vf4 hv = *(const vf4*)&h_in[(unpack_col(e0, r) << 5) + bo];
            accA += unpack_val(e0) * hv;
        }
        vf4 acc = accA + accB;
        float bv = bias[r];
        vf4 o;
        o.x = fmaxf(acc.x + bv, 0.f);
        o.y = fmaxf(acc.y + bv, 0.f);
        o.z = fmaxf(acc.z + bv, 0.f);
        o.w = fmaxf(acc.w + bv, 0.f);
        *(vf4*)&h_out[(r << 5) + bo] = o;
    } else {
        // ---------------- long path ----------------
        __shared__ vf4 red[256];
        const int lcnt = *long_cnt;
        const int g  = threadIdx.x >> 3;      // entry group 0..31
        const int bo = (threadIdx.x & 7) * 4; // batch offset
        for (int li = (int)blockIdx.x - SGRID; li < lcnt; li += LGRID) {
            int r = long_list[li];
            int s = row_ptr[r];
            int n = row_ptr[r + 1] - s;
            const unsigned int* __restrict__ p = csr4 + s;
            vf4 a0 = (vf4)(0.f);
            vf4 a1 = (vf4)(0.f);
            int i = g;
            for (; i + 32 < n; i += 64) {
                unsigned int e0 = p[i];
                unsigned int e1 = p[i + 32];
                vf4 h0 = *(const vf4*)&h_in[(unpack_col(e0, r) << 5) + bo];
                vf4 h1 = *(const vf4*)&h_in[(unpack_col(e1, r) << 5) + bo];
                a0 += unpack_val(e0) * h0;
                a1 += unpack_val(e1) * h1;
            }
            if (i < n) {
                unsigned int e0 = p[i];
                vf4 hv = *(const vf4*)&h_in[(unpack_col(e0, r) << 5) + bo];
                a0 += unpack_val(e0) * hv;
            }
            red[threadIdx.x] = a0 + a1;
            __syncthreads();
            if (threadIdx.x < 64) {
                vf4 a = red[threadIdx.x] + red[threadIdx.x + 64] +
                        red[threadIdx.x + 128] + red[threadIdx.x + 192];
                red[threadIdx.x] = a;
            }
            __syncthreads();
            if (threadIdx.x < 8) {
                vf4 a = (vf4)(0.f);
                #pragma unroll
                for (int k = 0; k < 8; ++k) a += red[k * 8 + threadIdx.x];
                float bv = bias[r];
                vf4 o;
                o.x = fmaxf(a.x + bv, 0.f);
                o.y = fmaxf(a.y + bv, 0.f);
                o.z = fmaxf(a.z + bv, 0.f);
                o.w = fmaxf(a.w + bv, 0.f);
                *(vf4*)&h_out[(r << 5) + threadIdx.x * 4] = o;
            }
            __syncthreads();
        }
    }
}

// ---------------------------------------------------------------------------
// 6a) Split-K GEMM partials
__global__ __launch_bounds__(256) void gemm1_kernel(const float* __restrict__ h,
                                                    const float* __restrict__ w1,
                                                    float* __restrict__ partials) {
    int n0 = blockIdx.x * NCHUNK;
    int nend = n0 + NCHUNK; if (nend > NN) nend = NN;
    int j  = threadIdx.x & 63;
    int b0 = threadIdx.x >> 6;
    float sum[8];
    #pragma unroll
    for (int ii = 0; ii < 8; ++ii) sum[ii] = 0.f;
    for (int n = n0; n < nend; ++n) {
        float w = w1[n * 64 + j];
        #pragma unroll
        for (int ii = 0; ii < 8; ++ii)
            sum[ii] = fmaf(w, h[n * 32 + b0 + ii * 4], sum[ii]);
    }
    float* dst = partials + blockIdx.x * 2048;
    #pragma unroll
    for (int ii = 0; ii < 8; ++ii)
        dst[(b0 + ii * 4) * 64 + j] = sum[ii];
}

// 6b) Reduce partials -> acc (2048 cells)
__global__ __launch_bounds__(256) void gemm1_reduce(const float* __restrict__ partials,
                                                    float* __restrict__ acc) {
    int cell = blockIdx.x * 256 + threadIdx.x;
    float s0 = 0.f, s1 = 0.f, s2 = 0.f, s3 = 0.f;
    int k = 0;
    for (; k + 4 <= NPART; k += 4) {
        s0 += partials[(k + 0) * 2048 + cell];
        s1 += partials[(k + 1) * 2048 + cell];
        s2 += partials[(k + 2) * 2048 + cell];
        s3 += partials[(k + 3) * 2048 + cell];
    }
    for (; k < NPART; ++k) s0 += partials[k * 2048 + cell];
    acc[cell] = (s0 + s1) + (s2 + s3);
}

// ---------------------------------------------------------------------------
// 7) Head
__global__ __launch_bounds__(320) void head_kernel(const float* __restrict__ acc,
                                                   const float* __restrict__ b1,
                                                   const float* __restrict__ w2,
                                                   const float* __restrict__ b2,
                                                   float* __restrict__ out) {
    int t = threadIdx.x;
    if (t >= 320) return;
    int b = t / 10, oj = t % 10;
    float s = b2[oj];
    #pragma unroll
    for (int k = 0; k < 64; ++k)
        s += fmaxf(acc[b * 64 + k] + b1[k], 0.f) * w2[k * 10 + oj];
    out[b * 10 + oj] = s;
}

// ---------------------------------------------------------------------------
extern "C" void kernel_launch(void* const* d_in, const int* in_sizes, int n_in,
                              void* d_out, int out_size, void* d_ws, size_t ws_size,
                              hipStream_t stream) {
    const float* x    = (const float*)d_in[0];
    const float* vals = (const float*)d_in[1];
    const float* bias = (const float*)d_in[2];
    const float* w1   = (const float*)d_in[3];
    const float* b1   = (const float*)d_in[4];
    const float* w2   = (const float*)d_in[5];
    const float* b2   = (const float*)d_in[6];
    const int*   rows = (const int*)d_in[7];
    float* out = (float*)d_out;

    // workspace layout
    const int NB = NN * BATCH;                    // 1,440,000 floats
    float*        hA        = (float*)d_ws;
    float*        hB        = hA + NB;
    int*          row_ptr   = (int*)(hB + NB);            // NPAD ints
    int*          cursor    = row_ptr + NPAD;             // NPAD ints
    unsigned int* csr4      = (unsigned int*)(cursor + NPAD);  // NNZ u32
    float*        partials  = (float*)(csr4 + NNZ);       // NPART*2048 floats
    float*        acc       = partials + NPART * 2048;    // 2048 floats
    int*          long_cnt  = (int*)(acc + 2048);         // 1 int
    int*          long_list = long_cnt + 8;               // NPAD ints

    // ---- CSR-transpose build ----
    hipMemsetAsync(cursor, 0, NN * sizeof(int), stream);
    hipMemsetAsync(long_cnt, 0, sizeof(int), stream);
    hist_kernel<<<(NNZ + 255) / 256, 256, 0, stream>>>(rows, cursor);
    scan_kernel<<<1, 1024, 0, stream>>>(cursor, row_ptr);
    hipMemcpyAsync(cursor, row_ptr, NN * sizeof(int), hipMemcpyDeviceToDevice, stream);
    scatter_kernel<<<(NNZ + 255) / 256, 256, 0, stream>>>(rows, vals, cursor, csr4);
    classify_kernel<<<(NN + 255) / 256, 256, 0, stream>>>(row_ptr, long_list, long_cnt);

    // ---- h0 = x.T ----
    init_kernel<<<(NN + 63) / 64, 256, 0, stream>>>(x, hA);

    // ---- T recurrent steps ----
    float* bufs[2] = { hA, hB };
    for (int t = 0; t < TSTEPS; ++t) {
        step_kernel<<<STEP_BLOCKS, 256, 0, stream>>>(
            row_ptr, csr4, bias, bufs[t & 1], bufs[(t + 1) & 1],
            long_list, long_cnt);
    }
    float* hfin = bufs[TSTEPS & 1];

    // ---- MLP head ----
    gemm1_kernel<<<NPART, 256, 0, stream>>>(hfin, w1, partials);
    gemm1_reduce<<<8, 256, 0, stream>>>(partials, acc);
    head_kernel<<<1, 320, 0, stream>>>(acc, b1, w2, b2, out);
}